// Round 9
// baseline (7162.404 us; speedup 1.0000x reference)
//
#include <hip/hip_runtime.h>
#include <cmath>

#define HH 512
#define NV 4
#define ED 64
#define NB 64
#define NT 512

#define NWG  256
#define NTHR 512     // 8 col-pairs x 64 k-lanes; 8 waves -> 2 waves/SIMD
#define WPG  32      // workgroups per group
#define RPG  8       // batch rows per group
#define CPW  16      // output cols per WG

#define HPAR (NB * HH)          // parity stride in h buffers (32768 floats)

// LDS (floats): in0[8][1024] | in1[8][1024] | in2[8][1024] = 24576 fl (96 KB)
#define IN0_OFF 0
#define IN1_OFF (8 * 1024)                // 8192
#define IN2_OFF (16 * 1024)               // 16384
#define LDS_FLOATS (IN2_OFF + 8 * 1024)   // 24576 used
#define LDS_BYTES_ALLOC 98304             // 96 KB (1 WG/CU)

// ws ints (zeroed at launch):
//  [0 .. 8191]      per-WG phase flags, ONE 128B LINE EACH: flag(g,cb) at (g*32+cb)*32
//  [8192]           global one-shot counter
//  [8704 .. 8959]   xcdtab[bid]
#define WS_INT_FLOATS 9216
#define FLAG(g, cb) (((g) * 32 + (cb)) * 32)

// ---- device-coherent (MALL) scalar access -------------------------------
static __device__ __forceinline__ float gld(const float* p) {
  return __hip_atomic_load(p, __ATOMIC_RELAXED, __HIP_MEMORY_SCOPE_AGENT);
}
static __device__ __forceinline__ void gst(float* p, float v) {
  __hip_atomic_store(p, v, __ATOMIC_RELAXED, __HIP_MEMORY_SCOPE_AGENT);
}

// ---- group barrier: per-WG phase flag on its OWN cache line --------------
static __device__ __forceinline__ void gbar_arrive(int* flags, int g, int cb,
                                                   int ph) {
  asm volatile("s_waitcnt vmcnt(0)" ::: "memory");  // data stores at MALL/L2
  __syncthreads();
  if (threadIdx.x == 0)
    __hip_atomic_store(flags + FLAG(g, cb), ph, __ATOMIC_RELAXED,
                       __HIP_MEMORY_SCOPE_AGENT);
}
static __device__ __forceinline__ void gbar_wait(int* flags, int g, int ph) {
  if (threadIdx.x < 64) {
    const int* f = flags + FLAG(g, threadIdx.x & 31);
    while (__hip_atomic_load(f, __ATOMIC_RELAXED,
                             __HIP_MEMORY_SCOPE_AGENT) < ph)
      __builtin_amdgcn_s_sleep(1);
  }
  __syncthreads();
  asm volatile("" ::: "memory");
}
static __device__ __forceinline__ void gbar(int* flags, int g, int cb, int ph) {
  gbar_arrive(flags, g, cb, ph);
  gbar_wait(flags, g, ph);
}

static __device__ __forceinline__ void gbar_all(int* ctr) {
  asm volatile("s_waitcnt vmcnt(0)" ::: "memory");
  __syncthreads();
  if (threadIdx.x == 0) {
    __hip_atomic_fetch_add(ctr, 1, __ATOMIC_RELAXED, __HIP_MEMORY_SCOPE_AGENT);
    while (__hip_atomic_load(ctr, __ATOMIC_RELAXED,
                             __HIP_MEMORY_SCOPE_AGENT) < NWG)
      __builtin_amdgcn_s_sleep(1);
  }
  __syncthreads();
  asm volatile("" ::: "memory");
}

// ---- staging: one 8x512 half-tile = 2 x dwordx4 per thread --------------
template <bool COH>
static __device__ __forceinline__ void half_issue(const float* src, int row0,
                                                  float4 (&v)[2]) {
#pragma unroll
  for (int j = 0; j < 2; ++j) {
    const int qq = threadIdx.x + NTHR * j;
    const int row = qq >> 7, kq = qq & 127;
    const float* p = src + (size_t)(row0 + row) * HH + (kq << 2);
    if (COH) asm volatile("global_load_dwordx4 %0, %1, off sc0" : "=v"(v[j]) : "v"(p));
    else     asm volatile("global_load_dwordx4 %0, %1, off sc0 sc1" : "=v"(v[j]) : "v"(p));
  }
}
static __device__ __forceinline__ void half_commit(float* lds, int off,
                                                   int kofs, const float4 (&v)[2]) {
#pragma unroll
  for (int j = 0; j < 2; ++j) {
    const int qq = threadIdx.x + NTHR * j;
    const int row = qq >> 7, kq = qq & 127;
    *(float4*)(lds + off + row * 1024 + kofs + (kq << 2)) = v[j];
  }
}
static __device__ __forceinline__ void stage_half(float* lds, int off,
                                                  const float* src, int row0,
                                                  int kofs, int coh) {
  float4 v[2];
  if (coh) half_issue<true>(src, row0, v);
  else     half_issue<false>(src, row0, v);
  asm volatile("s_waitcnt vmcnt(0)" ::: "memory");
  __builtin_amdgcn_sched_barrier(0);
  half_commit(lds, off, kofs, v);
}

// pf loads are inline-asm: the compiler's waitcnt bookkeeping does NOT
// cover them. ALWAYS drain before committing pf registers to LDS.
#define PF_DRAIN() \
  do { asm volatile("s_waitcnt vmcnt(0)" ::: "memory"); \
       __builtin_amdgcn_sched_barrier(0); } while (0)

// ---- weights: per thread, per col: 4 quads of 4 floats (k = q*256+ks*4) --
static __device__ __forceinline__ void unpk(float (&w)[16], int q, float4 v) {
  w[4*q+0] = v.x; w[4*q+1] = v.y; w[4*q+2] = v.z; w[4*q+3] = v.w;
}
// standard 1024-K layer: tile = [ih input (0..511) | hh input (512..1023)]
static __device__ __forceinline__ void load_wq(float (&w)[16], const float* ih,
                                               const float* hh, int col, int ks) {
  unpk(w, 0, *(const float4*)(ih + (size_t)col * HH + ks * 4));
  unpk(w, 1, *(const float4*)(ih + (size_t)col * HH + 256 + ks * 4));
  unpk(w, 2, *(const float4*)(hh + (size_t)col * HH + ks * 4));
  unpk(w, 3, *(const float4*)(hh + (size_t)col * HH + 256 + ks * 4));
}
// encoder l0: tile = [emb (0..63) | h (64..575) | ZERO (576..1023)]
static __device__ __forceinline__ void load_wq0(float (&w)[16], const float* e,
                                                const float* hh, int col, int ks) {
  const float4 z = make_float4(0.f, 0.f, 0.f, 0.f);
  unpk(w, 0, (ks < 16) ? *(const float4*)(e + (size_t)col * ED + ks * 4)
                       : *(const float4*)(hh + (size_t)col * HH + (ks * 4 - 64)));
  unpk(w, 1, *(const float4*)(hh + (size_t)col * HH + 192 + ks * 4));
  unpk(w, 2, (ks < 16) ? *(const float4*)(hh + (size_t)col * HH + 448 + ks * 4) : z);
  unpk(w, 3, z);
}

// ---- half-tile accumulate (quads q0, q0+1) ------------------------------
static __device__ __forceinline__ void tile_acc2(
    float (&a)[16], const float* lds, int tile_off, int q0,
    const float (&wA)[16], const float (&wB)[16]) {
  const int lane = threadIdx.x & 63;
  const float* base = lds + tile_off + lane * 4;
#pragma unroll
  for (int r = 0; r < 8; ++r) {
    const float* rb = base + r * 1024;
#pragma unroll
    for (int qq = 0; qq < 2; ++qq) {
      const int q = q0 + qq;
      const float4 iv = *(const float4*)(rb + q * 256);
      a[2*r+0] = fmaf(wA[4*q+0], iv.x, a[2*r+0]);
      a[2*r+0] = fmaf(wA[4*q+1], iv.y, a[2*r+0]);
      a[2*r+0] = fmaf(wA[4*q+2], iv.z, a[2*r+0]);
      a[2*r+0] = fmaf(wA[4*q+3], iv.w, a[2*r+0]);
      a[2*r+1] = fmaf(wB[4*q+0], iv.x, a[2*r+1]);
      a[2*r+1] = fmaf(wB[4*q+1], iv.y, a[2*r+1]);
      a[2*r+1] = fmaf(wB[4*q+2], iv.z, a[2*r+1]);
      a[2*r+1] = fmaf(wB[4*q+3], iv.w, a[2*r+1]);
    }
  }
}
static __device__ __forceinline__ void zero16(float (&a)[16]) {
#pragma unroll
  for (int v = 0; v < 16; ++v) a[v] = 0.f;
}

// ---- 17-shuffle in-wave split-reduce + tanh + store ----------------------
static __device__ __forceinline__ void tile_finish(
    float (&a)[16], float bA, float bB,
    float* dst, float* dst2, int row0, int colA, int coh) {
  const int lane = threadIdx.x & 63;
#pragma unroll
  for (int i = 0; i < 8; ++i) {
    const float send = (lane & 32) ? a[i] : a[i + 8];
    const float recv = __shfl_xor(send, 32);
    const float keep = (lane & 32) ? a[i + 8] : a[i];
    a[i] = keep + recv;
  }
#pragma unroll
  for (int i = 0; i < 4; ++i) {
    const float send = (lane & 16) ? a[i] : a[i + 4];
    const float recv = __shfl_xor(send, 16);
    const float keep = (lane & 16) ? a[i + 4] : a[i];
    a[i] = keep + recv;
  }
#pragma unroll
  for (int i = 0; i < 2; ++i) {
    const float send = (lane & 8) ? a[i] : a[i + 2];
    const float recv = __shfl_xor(send, 8);
    const float keep = (lane & 8) ? a[i + 2] : a[i];
    a[i] = keep + recv;
  }
  {
    const float send = (lane & 4) ? a[0] : a[1];
    const float recv = __shfl_xor(send, 4);
    const float keep = (lane & 4) ? a[1] : a[0];
    a[0] = keep + recv;
  }
  a[0] += __shfl_xor(a[0], 1);
  a[0] += __shfl_xor(a[0], 2);
  if ((lane & 3) == 0) {
    const int r  = ((lane >> 5) & 1) * 4 + ((lane >> 4) & 1) * 2 + ((lane >> 3) & 1);
    const int cc = (lane >> 2) & 1;
    const float h = tanhf(a[0] + (cc ? bB : bA));
    const size_t idx = (size_t)(row0 + r) * HH + colA + cc;
    if (coh) { dst[idx] = h; if (dst2) dst2[idx] = h; }
    else     { gst(dst + idx, h); if (dst2) gst(dst2 + idx, h); }
  }
}

// ---- full layer tile (decoder t=0 peel) ----------------------------------
static __device__ __forceinline__ void layer_tile(
    float* lds, int tile_off,
    const float (&wA)[16], const float (&wB)[16], float bA, float bB,
    float* dst, float* dst2, int row0, int colA, int coh) {
  __syncthreads();                  // staging visible
  float a[16];
  zero16(a);
  tile_acc2(a, lds, tile_off, 0, wA, wB);
  tile_acc2(a, lds, tile_off, 2, wA, wB);
  __syncthreads();                  // all reads done -> tile reusable
  tile_finish(a, bA, bB, dst, dst2, row0, colA, coh);
}

// ---- projection + log_softmax for one batch row (wave0 of cb<8 WGs) -----
static __device__ __forceinline__ void proj_row(const float* lds, int tile_off,
                                                int r_local, const float* projw,
                                                float* out, int row, int tt) {
  const int lane = threadIdx.x;       // < 64
  const int v = lane & 3, kq = lane >> 2;
  float acc = 0.f;
#pragma unroll
  for (int i8 = 0; i8 < 8; ++i8) {
    const int k = (kq << 5) + (i8 << 2);
    const float4 iv = *(const float4*)(lds + tile_off + r_local * 1024 + k);
    const float4 wv = *(const float4*)(projw + (size_t)v * HH + k);
    acc = fmaf(iv.x, wv.x, acc);
    acc = fmaf(iv.y, wv.y, acc);
    acc = fmaf(iv.z, wv.z, acc);
    acc = fmaf(iv.w, wv.w, acc);
  }
  acc += __shfl_xor(acc, 4);
  acc += __shfl_xor(acc, 8);
  acc += __shfl_xor(acc, 16);
  acc += __shfl_xor(acc, 32);
  float m = fmaxf(acc, __shfl_xor(acc, 1));
  m = fmaxf(m, __shfl_xor(m, 2));
  const float e = expf(acc - m);
  float sum = e + __shfl_xor(e, 1);
  sum += __shfl_xor(sum, 2);
  const float res = acc - m - logf(sum);
  if (lane < 4) out[((size_t)row * NT + tt) * NV + lane] = res;
}

#define STG(off, src, kofs) stage_half(lds, off, src, row0, kofs, coh)
#define PF_ISSUE(src) \
  do { if (coh) half_issue<true>(src, row0, pf); \
       else     half_issue<false>(src, row0, pf); } while (0)
#define PF1_ISSUE(src) \
  do { if (coh) half_issue<true>(src, row0, pf1); \
       else     half_issue<false>(src, row0, pf1); } while (0)
#define PF2_ISSUE(src) \
  do { if (coh) half_issue<true>(src, row0, pf2); \
       else     half_issue<false>(src, row0, pf2); } while (0)

__global__ void __launch_bounds__(NTHR, 2) rnn_ae(
    const float* __restrict__ x, const float* __restrict__ emb,
    const float* __restrict__ ew_ih0, const float* __restrict__ ew_ihr,
    const float* __restrict__ ew_hh, const float* __restrict__ eb_ih,
    const float* __restrict__ eb_hh,
    const float* __restrict__ dw_ih, const float* __restrict__ dw_hh,
    const float* __restrict__ db_ih, const float* __restrict__ db_hh,
    const float* __restrict__ projw,
    float* __restrict__ out, float* __restrict__ ws) {
  extern __shared__ float lds[];

  const int tid = threadIdx.x;
  const int bid = blockIdx.x;
  const int c   = tid >> 6;      // wave = col-pair 0..7
  const int ks  = tid & 63;      // k-lane 0..63

  int* flags  = (int*)ws;            // line-spread phase flags
  int* gctr   = (int*)ws + 8192;
  int* xcdtab = (int*)ws + 8704;
  float* h0  = ws + WS_INT_FLOATS;
  float* h1  = h0 + 2 * HPAR;
  float* h2  = h1 + 2 * HPAR;
  float* e0  = h2 + 2 * HPAR;
  float* e1  = e0 + 2 * HPAR;
  float* e2  = e1 + 2 * HPAR;
  float* xfb = e2 + 2 * HPAR;
  int ph = 0;

  // ------------- publish my XCD id ---------------------------------------
  unsigned xcc;
  asm volatile("s_getreg_b32 %0, hwreg(HW_REG_XCC_ID)" : "=s"(xcc));
  if (tid == 0)
    __hip_atomic_store(xcdtab + bid, (int)xcc, __ATOMIC_RELAXED,
                       __HIP_MEMORY_SCOPE_AGENT);

  // ------------- init: zero LDS, zero parity-1 h (bid-based cover) --------
  for (int i = tid; i < LDS_FLOATS; i += NTHR) lds[i] = 0.f;
  {
    const int zg = bid & 7, zcb = bid >> 3;
    for (int i = zcb * NTHR + tid; i < RPG * HH; i += WPG * NTHR) {
      const int r = i >> 9, cc = i & 511;
      const size_t o = HPAR + (size_t)(zg * RPG + r) * HH + cc;
      gst(h0 + o, 0.f); gst(h1 + o, 0.f); gst(h2 + o, 0.f);
    }
  }

  gbar_all(gctr);

  // ------------- XCD-aware regrouping (census; proven in R4/R8) -----------
  int g, cb, coh;
  {
    int* ldsX = (int*)(lds + IN1_OFF);       // scratch; IN1 ih region is
                                             // overwritten before first read
    if (tid < NWG)
      ldsX[tid] = __hip_atomic_load(xcdtab + tid, __ATOMIC_RELAXED,
                                    __HIP_MEMORY_SCOPE_AGENT);
    __syncthreads();
    const int myx = ldsX[bid] & 7;
    unsigned long long cnt = 0;
    int rank = 0;
    for (int b = 0; b < NWG; ++b) {
      const int xb = ldsX[b] & 7;
      cnt += 1ull << (xb * 8);
      if (b < bid && xb == myx) ++rank;
    }
    if (cnt == 0x2020202020202020ull) {      // all 8 XCDs have exactly 32
      g = myx; cb = rank; coh = 1;
    } else {
      g = bid & 7; cb = bid >> 3;
      coh = 1;
      const int x0 = ldsX[g] & 7;
      for (int j = 1; j < WPG; ++j)
        coh &= ((ldsX[g + 8 * j] & 7) == x0);
    }
    __syncthreads();                         // done with ldsX
    if (tid < NWG) ldsX[tid] = 0;            // re-zero scratched IN1 region
    __syncthreads();
  }
  const int row0 = g * RPG;
  const int col0 = cb * CPW;
  const int colA = col0 + 2 * c;
  const int colB = colA + 1;

  // ------------- load enc weights (depend on remapped col) ----------------
  float wA0[16], wB0[16], wA1[16], wB1[16], wA2[16], wB2[16];
  float bA0, bB0, bA1, bB1, bA2, bB2;
  load_wq0(wA0, ew_ih0, ew_hh, colA, ks);
  load_wq0(wB0, ew_ih0, ew_hh, colB, ks);
  load_wq(wA1, ew_ihr,                ew_hh + (size_t)HH * HH,     colA, ks);
  load_wq(wB1, ew_ihr,                ew_hh + (size_t)HH * HH,     colB, ks);
  load_wq(wA2, ew_ihr + (size_t)HH * HH, ew_hh + (size_t)2 * HH * HH, colA, ks);
  load_wq(wB2, ew_ihr + (size_t)HH * HH, ew_hh + (size_t)2 * HH * HH, colB, ks);
  bA0 = eb_ih[0*HH + colA] + eb_hh[0*HH + colA];
  bB0 = eb_ih[0*HH + colB] + eb_hh[0*HH + colB];
  bA1 = eb_ih[1*HH + colA] + eb_hh[1*HH + colA];
  bB1 = eb_ih[1*HH + colB] + eb_hh[1*HH + colB];
  bA2 = eb_ih[2*HH + colA] + eb_hh[2*HH + colA];
  bB2 = eb_ih[2*HH + colB] + eb_hh[2*HH + colB];

  // ------------- encoder: fused 3-layer pipeline, split-wait rounds -------
  // hh halves of l1/l2 are 2-barrier-old -> prefetched across the barrier
  // (pf1/pf2, own IN1/IN2 tiles); their partial FMA hides wait + load RT.
  float4 pf1[2], pf2[2];
  for (int s = 0; s <= NT + 1; ++s) {
    const bool l0a = s < NT;
    const bool l1a = (s >= 1) && (s < NT + 1);
    const bool l2a = s >= 2;

    // ---- pre-wait: commit prefetched hh halves, l1-hh partial -----------
    if (l1a || l2a) {
      PF_DRAIN();                            // pf regs valid before commit
      if (l1a) half_commit(lds, IN1_OFF, 512, pf1);
      if (l2a) half_commit(lds, IN2_OFF, 512, pf2);
      __syncthreads();
    }
    float A0[16], A1[16], A2[16];
    if (l1a) { zero16(A1); tile_acc2(A1, lds, IN1_OFF, 2, wA1, wB1); }

    gbar_wait(flags, g, ph);                 // peers' round s-1 data visible

    // ---- post-wait: issue 1-barrier-old loads; l2-hh partial hides RT ---
    float4 v0[2], v1a[2], v2a[2];
    if (l0a) {
      if (coh) half_issue<true>(h0 + ((s&1)^1) * HPAR, row0, v0);
      else     half_issue<false>(h0 + ((s&1)^1) * HPAR, row0, v0);
    }
    if (l1a) {
      if (coh) half_issue<true>(h0 + ((s-1)&1) * HPAR, row0, v1a);
      else     half_issue<false>(h0 + ((s-1)&1) * HPAR, row0, v1a);
    }
    if (l2a) {
      if (coh) half_issue<true>(h1 + ((s-2)&1) * HPAR, row0, v2a);
      else     half_issue<false>(h1 + ((s-2)&1) * HPAR, row0, v2a);
    }
    if (l2a) { zero16(A2); tile_acc2(A2, lds, IN2_OFF, 2, wA2, wB2); }
    PF_DRAIN();
    if (l0a) {                               // l0 tile: emb + hprev (IN0)
      half_commit(lds, IN0_OFF, 64, v0);
      if (tid < 128) {
        const int r = tid >> 4, i8 = tid & 15;
        const float* xr = x + ((size_t)(row0 + r) * NT + s) * NV;
        const float a0 = xr[0], a1 = xr[1], a2 = xr[2], a3 = xr[3];
        int idx = 0; float m = a0;
        if (a1 > m) { m = a1; idx = 1; }
        if (a2 > m) { m = a2; idx = 2; }
        if (a3 > m) { m = a3; idx = 3; }
        const int k = i8 << 2;
        *(float4*)(lds + IN0_OFF + r * 1024 + k) =
            *(const float4*)(emb + idx * ED + k);
      }
    }
    if (l1a) half_commit(lds, IN1_OFF, 0, v1a);
    if (l2a) half_commit(lds, IN2_OFF, 0, v2a);
    __syncthreads();

    // ---- compute + finish ----------------------------------------------
    if (l0a) {
      zero16(A0);
      tile_acc2(A0, lds, IN0_OFF, 0, wA0, wB0);
      tile_acc2(A0, lds, IN0_OFF, 2, wA0, wB0);
      tile_finish(A0, bA0, bB0, h0 + (s&1) * HPAR, nullptr, row0, colA, coh);
    }
    if (l1a) {
      tile_acc2(A1, lds, IN1_OFF, 0, wA1, wB1);
      tile_finish(A1, bA1, bB1, h1 + ((s-1)&1) * HPAR, nullptr, row0, colA, coh);
    }
    if (l2a) {
      tile_acc2(A2, lds, IN2_OFF, 0, wA2, wB2);
      tile_finish(A2, bA2, bB2, h2 + ((s-2)&1) * HPAR, nullptr, row0, colA, coh);
    }

    gbar_arrive(flags, g, cb, ++ph);         // drain h stores, post flag
    // prefetch next round's hh halves (2-barrier-old at use)
    if (s < NT)             PF1_ISSUE(h1 + ((s&1)^1) * HPAR);
    if (s >= 1 && s <= NT)  PF2_ISSUE(h2 + (((s-1)&1)^1) * HPAR);
  }
  gbar_wait(flags, g, ph);                   // finals visible for transition

  // ------------- transition: flip finals -> dec h0, load dec weights ------
  for (int i = cb * NTHR + tid; i < RPG * HH; i += WPG * NTHR) {
    const int r = i >> 9, cc = i & 511;
    const size_t o = HPAR + (size_t)(row0 + r) * HH + cc;
    const float a = gld(h2 + o);
    const float b = gld(h1 + o);
    const float cv = gld(h0 + o);
    if (coh) { e0[o] = a; e1[o] = b; e2[o] = cv; xfb[o] = 0.f; }
    else     { gst(e0 + o, a); gst(e1 + o, b); gst(e2 + o, cv); gst(xfb + o, 0.f); }
  }
  load_wq(wA0, dw_ih,                     dw_hh,                     colA, ks);
  load_wq(wB0, dw_ih,                     dw_hh,                     colB, ks);
  load_wq(wA1, dw_ih + (size_t)HH * HH,   dw_hh + (size_t)HH * HH,   colA, ks);
  load_wq(wB1, dw_ih + (size_t)HH * HH,   dw_hh + (size_t)HH * HH,   colB, ks);
  load_wq(wA2, dw_ih + (size_t)2*HH*HH,   dw_hh + (size_t)2*HH*HH,   colA, ks);
  load_wq(wB2, dw_ih + (size_t)2*HH*HH,   dw_hh + (size_t)2*HH*HH,   colB, ks);
  bA0 = db_ih[0*HH + colA] + db_hh[0*HH + colA];
  bB0 = db_ih[0*HH + colB] + db_hh[0*HH + colB];
  bA1 = db_ih[1*HH + colA] + db_hh[1*HH + colA];
  bB1 = db_ih[1*HH + colB] + db_hh[1*HH + colB];
  bA2 = db_ih[2*HH + colA] + db_hh[2*HH + colA];
  bB2 = db_ih[2*HH + colB] + db_hh[2*HH + colB];
  gbar(flags, g, cb, ++ph);

  // ------------- decoder t = 0 (peeled, original full-gbar structure) -----
  float4 pf[2];
  {
    const int p = 0, q = 1;
    STG(IN1_OFF, e0 + q * HPAR, 512);
    STG(IN1_OFF, xfb + q * HPAR, 0);
    __syncthreads();
    layer_tile(lds, IN1_OFF, wA0, wB0, bA0, bB0, e0 + p * HPAR, nullptr,
               row0, colA, coh);
    PF_ISSUE(e1 + q * HPAR);
    gbar(flags, g, cb, ++ph);

    half_commit(lds, IN1_OFF, 512, pf);
    STG(IN1_OFF, e0 + p * HPAR, 0);
    __syncthreads();
    layer_tile(lds, IN1_OFF, wA1, wB1, bA1, bB1, e1 + p * HPAR, nullptr,
               row0, colA, coh);
    PF_ISSUE(e2 + q * HPAR);
    gbar(flags, g, cb, ++ph);

    half_commit(lds, IN1_OFF, 512, pf);
    STG(IN1_OFF, e1 + p * HPAR, 0);
    __syncthreads();
    layer_tile(lds, IN1_OFF, wA2, wB2, bA2, bB2, e2 + p * HPAR,
               xfb + p * HPAR, row0, colA, coh);
    PF_ISSUE(e0 + p * HPAR);                 // t=1 l0's hprev (q' = p = 0)
    gbar(flags, g, cb, ++ph);
  }

  // ------------- decoder t >= 1: split phases (hh-compute hides the wait) -
  for (int t = 1; t < NT; ++t) {
    const int p = t & 1, q = p ^ 1;

    // ---- layer 0: cur = xfb[q], hprev = e0[q] (pf) ----
    PF_DRAIN();                              // pf regs valid before commit
    half_commit(lds, IN1_OFF, 512, pf);      // hprev -> hh half
    __syncthreads();
    float a0[16]; zero16(a0);
    tile_acc2(a0, lds, IN1_OFF, 2, wA0, wB0);   // hh compute while peers finish
    gbar_wait(flags, g, ph);                    // peers' xfb(t-1) now in L2
    STG(IN1_OFF, xfb + q * HPAR, 0);
    __syncthreads();
    if (cb < 8 && tid < 64)
      proj_row(lds, IN1_OFF, cb, projw, out, row0 + cb, t - 1);
    tile_acc2(a0, lds, IN1_OFF, 0, wA0, wB0);   // ih half
    tile_finish(a0, bA0, bB0, e0 + p * HPAR, nullptr, row0, colA, coh);
    gbar_arrive(flags, g, cb, ++ph);            // drain h stores, post flag
    PF_ISSUE(e1 + q * HPAR);                    // flies across next phase top

    // ---- layer 1: cur = e0[p], hprev = e1[q] (pf) ----
    PF_DRAIN();
    half_commit(lds, IN1_OFF, 512, pf);
    __syncthreads();
    float a1[16]; zero16(a1);
    tile_acc2(a1, lds, IN1_OFF, 2, wA1, wB1);
    gbar_wait(flags, g, ph);
    STG(IN1_OFF, e0 + p * HPAR, 0);
    __syncthreads();
    tile_acc2(a1, lds, IN1_OFF, 0, wA1, wB1);
    tile_finish(a1, bA1, bB1, e1 + p * HPAR, nullptr, row0, colA, coh);
    gbar_arrive(flags, g, cb, ++ph);
    PF_ISSUE(e2 + q * HPAR);

    // ---- layer 2: cur = e1[p], hprev = e2[q] (pf) ----
    PF_DRAIN();
    half_commit(lds, IN1_OFF, 512, pf);
    __syncthreads();
    float a2[16]; zero16(a2);
    tile_acc2(a2, lds, IN1_OFF, 2, wA2, wB2);
    gbar_wait(flags, g, ph);
    STG(IN1_OFF, e1 + p * HPAR, 0);
    __syncthreads();
    tile_acc2(a2, lds, IN1_OFF, 0, wA2, wB2);
    tile_finish(a2, bA2, bB2, e2 + p * HPAR, xfb + p * HPAR, row0, colA, coh);
    gbar_arrive(flags, g, cb, ++ph);
    PF_ISSUE(e0 + p * HPAR);                    // next step l0's hprev (q' = p)
  }

  // ------------- tail projection for t = NT-1 -----------------------------
  gbar_wait(flags, g, ph);                      // peers' xfb(t=NT-1) ready
  STG(IN1_OFF, xfb + ((NT - 1) & 1) * HPAR, 0);
  __syncthreads();
  if (cb < 8 && tid < 64)
    proj_row(lds, IN1_OFF, cb, projw, out, row0 + cb, NT - 1);
}

extern "C" void kernel_launch(void* const* d_in, const int* in_sizes, int n_in,
                              void* d_out, int out_size, void* d_ws, size_t ws_size,
                              hipStream_t stream) {
  const float* x      = (const float*)d_in[0];
  const float* emb    = (const float*)d_in[1];
  const float* ew_ih0 = (const float*)d_in[2];
  const float* ew_ihr = (const float*)d_in[3];
  const float* ew_hh  = (const float*)d_in[4];
  const float* eb_ih  = (const float*)d_in[5];
  const float* eb_hh  = (const float*)d_in[6];
  const float* dw_ih  = (const float*)d_in[7];
  const float* dw_hh  = (const float*)d_in[8];
  const float* db_ih  = (const float*)d_in[9];
  const float* db_hh  = (const float*)d_in[10];
  const float* projw  = (const float*)d_in[11];
  float* out = (float*)d_out;
  float* ws  = (float*)d_ws;

  (void)hipMemsetAsync(d_ws, 0, WS_INT_FLOATS * 4, stream);

  // 96 KB dynamic LDS: 2 WGs cannot share a CU -> deterministic 1 WG/CU.
  (void)hipFuncSetAttribute((const void*)rnn_ae,
                            hipFuncAttributeMaxDynamicSharedMemorySize,
                            LDS_BYTES_ALLOC);

  rnn_ae<<<dim3(NWG), dim3(NTHR), LDS_BYTES_ALLOC, stream>>>(
      x, emb, ew_ih0, ew_ihr, ew_hh, eb_ih, eb_hh,
      dw_ih, dw_hh, db_ih, db_hh, projw, out, ws);
}

// Round 10
// 6771.738 us; speedup vs baseline: 1.0577x; 1.0577x over previous
//
#include <hip/hip_runtime.h>
#include <cmath>

#define HH 512
#define NV 4
#define ED 64
#define NB 64
#define NT 512

#define NWG  256
#define NTHR 512     // 8 col-pairs x 64 k-lanes; 8 waves -> 2 waves/SIMD
#define WPG  32      // workgroups per group
#define RPG  8       // batch rows per group
#define CPW  16      // output cols per WG

#define HPAR (NB * HH)          // parity stride in h buffers (32768 floats)

// LDS (floats): in0[8][1024] | in1[8][1024] = 16384 fl (64 KB used)
// ALLOCATED 96 KB to force 1 WG/CU (deterministic placement).
#define IN0_OFF 0
#define IN1_OFF (8 * 1024)                // 8192
#define LDS_FLOATS (IN1_OFF + 8 * 1024)   // 16384 used
#define LDS_BYTES_ALLOC 98304             // 96 KB requested

// ws ints (zeroed at launch):
//  [0 .. 8191]      per-WG phase flags, ONE 128B LINE EACH: flag(g,cb) at (g*32+cb)*32
//  [8192]           global one-shot counter
//  [8704 .. 8959]   xcdtab[bid]
#define WS_INT_FLOATS 9216
#define FLAG(g, cb) (((g) * 32 + (cb)) * 32)

// ---- device-coherent (MALL) scalar access -------------------------------
static __device__ __forceinline__ float gld(const float* p) {
  return __hip_atomic_load(p, __ATOMIC_RELAXED, __HIP_MEMORY_SCOPE_AGENT);
}
static __device__ __forceinline__ void gst(float* p, float v) {
  __hip_atomic_store(p, v, __ATOMIC_RELAXED, __HIP_MEMORY_SCOPE_AGENT);
}

// ---- group barrier: per-WG phase flag on its OWN cache line --------------
// Flags MUST stay agent-scope (MALL): narrower-scope poll loads can hit a
// stale L1-resident flag line forever (R1/R2 hang mechanism).
static __device__ __forceinline__ void gbar_arrive(int* flags, int g, int cb,
                                                   int ph) {
  asm volatile("s_waitcnt vmcnt(0)" ::: "memory");  // data stores at MALL/L2
  __syncthreads();
  if (threadIdx.x == 0)
    __hip_atomic_store(flags + FLAG(g, cb), ph, __ATOMIC_RELAXED,
                       __HIP_MEMORY_SCOPE_AGENT);
}
static __device__ __forceinline__ void gbar_wait(int* flags, int g, int ph) {
  if (threadIdx.x < 64) {
    const int* f = flags + FLAG(g, threadIdx.x & 31);
    while (__hip_atomic_load(f, __ATOMIC_RELAXED,
                             __HIP_MEMORY_SCOPE_AGENT) < ph)
      __builtin_amdgcn_s_sleep(1);
  }
  __syncthreads();
  asm volatile("" ::: "memory");
}
static __device__ __forceinline__ void gbar(int* flags, int g, int cb, int ph) {
  gbar_arrive(flags, g, cb, ph);
  gbar_wait(flags, g, ph);
}

static __device__ __forceinline__ void gbar_all(int* ctr) {
  asm volatile("s_waitcnt vmcnt(0)" ::: "memory");
  __syncthreads();
  if (threadIdx.x == 0) {
    __hip_atomic_fetch_add(ctr, 1, __ATOMIC_RELAXED, __HIP_MEMORY_SCOPE_AGENT);
    while (__hip_atomic_load(ctr, __ATOMIC_RELAXED,
                             __HIP_MEMORY_SCOPE_AGENT) < NWG)
      __builtin_amdgcn_s_sleep(1);
  }
  __syncthreads();
  asm volatile("" ::: "memory");
}

// ---- staging: one 8x512 half-tile = 2 x dwordx4 per thread --------------
template <bool COH>
static __device__ __forceinline__ void half_issue(const float* src, int row0,
                                                  float4 (&v)[2]) {
#pragma unroll
  for (int j = 0; j < 2; ++j) {
    const int qq = threadIdx.x + NTHR * j;
    const int row = qq >> 7, kq = qq & 127;
    const float* p = src + (size_t)(row0 + row) * HH + (kq << 2);
    if (COH) asm volatile("global_load_dwordx4 %0, %1, off sc0" : "=v"(v[j]) : "v"(p));
    else     asm volatile("global_load_dwordx4 %0, %1, off sc0 sc1" : "=v"(v[j]) : "v"(p));
  }
}
static __device__ __forceinline__ void half_commit(float* lds, int off,
                                                   int kofs, const float4 (&v)[2]) {
#pragma unroll
  for (int j = 0; j < 2; ++j) {
    const int qq = threadIdx.x + NTHR * j;
    const int row = qq >> 7, kq = qq & 127;
    *(float4*)(lds + off + row * 1024 + kofs + (kq << 2)) = v[j];
  }
}
static __device__ __forceinline__ void stage_half(float* lds, int off,
                                                  const float* src, int row0,
                                                  int kofs, int coh) {
  float4 v[2];
  if (coh) half_issue<true>(src, row0, v);
  else     half_issue<false>(src, row0, v);
  asm volatile("s_waitcnt vmcnt(0)" ::: "memory");
  __builtin_amdgcn_sched_barrier(0);
  half_commit(lds, off, kofs, v);
}

// pf loads are inline-asm: the compiler's waitcnt bookkeeping does NOT
// cover them. ALWAYS drain before committing pf registers to LDS.
#define PF_DRAIN() \
  do { asm volatile("s_waitcnt vmcnt(0)" ::: "memory"); \
       __builtin_amdgcn_sched_barrier(0); } while (0)

// ---- weights: per thread, per col: 4 quads of 4 floats (k = q*256+ks*4) --
static __device__ __forceinline__ void unpk(float (&w)[16], int q, float4 v) {
  w[4*q+0] = v.x; w[4*q+1] = v.y; w[4*q+2] = v.z; w[4*q+3] = v.w;
}
// standard 1024-K layer: tile = [ih input (0..511) | hh input (512..1023)]
static __device__ __forceinline__ void load_wq(float (&w)[16], const float* ih,
                                               const float* hh, int col, int ks) {
  unpk(w, 0, *(const float4*)(ih + (size_t)col * HH + ks * 4));
  unpk(w, 1, *(const float4*)(ih + (size_t)col * HH + 256 + ks * 4));
  unpk(w, 2, *(const float4*)(hh + (size_t)col * HH + ks * 4));
  unpk(w, 3, *(const float4*)(hh + (size_t)col * HH + 256 + ks * 4));
}
// encoder l0: tile = [emb (0..63) | h (64..575) | ZERO (576..1023)]
static __device__ __forceinline__ void load_wq0(float (&w)[16], const float* e,
                                                const float* hh, int col, int ks) {
  const float4 z = make_float4(0.f, 0.f, 0.f, 0.f);
  unpk(w, 0, (ks < 16) ? *(const float4*)(e + (size_t)col * ED + ks * 4)
                       : *(const float4*)(hh + (size_t)col * HH + (ks * 4 - 64)));
  unpk(w, 1, *(const float4*)(hh + (size_t)col * HH + 192 + ks * 4));
  unpk(w, 2, (ks < 16) ? *(const float4*)(hh + (size_t)col * HH + 448 + ks * 4) : z);
  unpk(w, 3, z);
}

// ---- half-tile accumulate (quads q0, q0+1) ------------------------------
static __device__ __forceinline__ void tile_acc2(
    float (&a)[16], const float* lds, int tile_off, int q0,
    const float (&wA)[16], const float (&wB)[16]) {
  const int lane = threadIdx.x & 63;
  const float* base = lds + tile_off + lane * 4;
#pragma unroll
  for (int r = 0; r < 8; ++r) {
    const float* rb = base + r * 1024;
#pragma unroll
    for (int qq = 0; qq < 2; ++qq) {
      const int q = q0 + qq;
      const float4 iv = *(const float4*)(rb + q * 256);
      a[2*r+0] = fmaf(wA[4*q+0], iv.x, a[2*r+0]);
      a[2*r+0] = fmaf(wA[4*q+1], iv.y, a[2*r+0]);
      a[2*r+0] = fmaf(wA[4*q+2], iv.z, a[2*r+0]);
      a[2*r+0] = fmaf(wA[4*q+3], iv.w, a[2*r+0]);
      a[2*r+1] = fmaf(wB[4*q+0], iv.x, a[2*r+1]);
      a[2*r+1] = fmaf(wB[4*q+1], iv.y, a[2*r+1]);
      a[2*r+1] = fmaf(wB[4*q+2], iv.z, a[2*r+1]);
      a[2*r+1] = fmaf(wB[4*q+3], iv.w, a[2*r+1]);
    }
  }
}
static __device__ __forceinline__ void zero16(float (&a)[16]) {
#pragma unroll
  for (int v = 0; v < 16; ++v) a[v] = 0.f;
}

// ---- 17-shuffle in-wave split-reduce + tanh + store ----------------------
static __device__ __forceinline__ void tile_finish(
    float (&a)[16], float bA, float bB,
    float* dst, float* dst2, int row0, int colA, int coh) {
  const int lane = threadIdx.x & 63;
#pragma unroll
  for (int i = 0; i < 8; ++i) {
    const float send = (lane & 32) ? a[i] : a[i + 8];
    const float recv = __shfl_xor(send, 32);
    const float keep = (lane & 32) ? a[i + 8] : a[i];
    a[i] = keep + recv;
  }
#pragma unroll
  for (int i = 0; i < 4; ++i) {
    const float send = (lane & 16) ? a[i] : a[i + 4];
    const float recv = __shfl_xor(send, 16);
    const float keep = (lane & 16) ? a[i + 4] : a[i];
    a[i] = keep + recv;
  }
#pragma unroll
  for (int i = 0; i < 2; ++i) {
    const float send = (lane & 8) ? a[i] : a[i + 2];
    const float recv = __shfl_xor(send, 8);
    const float keep = (lane & 8) ? a[i + 2] : a[i];
    a[i] = keep + recv;
  }
  {
    const float send = (lane & 4) ? a[0] : a[1];
    const float recv = __shfl_xor(send, 4);
    const float keep = (lane & 4) ? a[1] : a[0];
    a[0] = keep + recv;
  }
  a[0] += __shfl_xor(a[0], 1);
  a[0] += __shfl_xor(a[0], 2);
  if ((lane & 3) == 0) {
    const int r  = ((lane >> 5) & 1) * 4 + ((lane >> 4) & 1) * 2 + ((lane >> 3) & 1);
    const int cc = (lane >> 2) & 1;
    const float h = tanhf(a[0] + (cc ? bB : bA));
    const size_t idx = (size_t)(row0 + r) * HH + colA + cc;
    if (coh) { dst[idx] = h; if (dst2) dst2[idx] = h; }
    else     { gst(dst + idx, h); if (dst2) gst(dst2 + idx, h); }
  }
}

// ---- full layer tile (encoder / decoder t=0 peel) ------------------------
static __device__ __forceinline__ void layer_tile(
    float* lds, int tile_off,
    const float (&wA)[16], const float (&wB)[16], float bA, float bB,
    float* dst, float* dst2, int row0, int colA, int coh) {
  __syncthreads();                  // staging visible
  float a[16];
  zero16(a);
  tile_acc2(a, lds, tile_off, 0, wA, wB);
  tile_acc2(a, lds, tile_off, 2, wA, wB);
  __syncthreads();                  // all reads done -> tile reusable
  tile_finish(a, bA, bB, dst, dst2, row0, colA, coh);
}

// ---- projection + log_softmax for one batch row (wave0 of cb<8 WGs) -----
static __device__ __forceinline__ void proj_row(const float* lds, int tile_off,
                                                int r_local, const float* projw,
                                                float* out, int row, int tt) {
  const int lane = threadIdx.x;       // < 64
  const int v = lane & 3, kq = lane >> 2;
  float acc = 0.f;
#pragma unroll
  for (int i8 = 0; i8 < 8; ++i8) {
    const int k = (kq << 5) + (i8 << 2);
    const float4 iv = *(const float4*)(lds + tile_off + r_local * 1024 + k);
    const float4 wv = *(const float4*)(projw + (size_t)v * HH + k);
    acc = fmaf(iv.x, wv.x, acc);
    acc = fmaf(iv.y, wv.y, acc);
    acc = fmaf(iv.z, wv.z, acc);
    acc = fmaf(iv.w, wv.w, acc);
  }
  acc += __shfl_xor(acc, 4);
  acc += __shfl_xor(acc, 8);
  acc += __shfl_xor(acc, 16);
  acc += __shfl_xor(acc, 32);
  float m = fmaxf(acc, __shfl_xor(acc, 1));
  m = fmaxf(m, __shfl_xor(m, 2));
  const float e = expf(acc - m);
  float sum = e + __shfl_xor(e, 1);
  sum += __shfl_xor(sum, 2);
  const float res = acc - m - logf(sum);
  if (lane < 4) out[((size_t)row * NT + tt) * NV + lane] = res;
}

#define STG(off, src, kofs) stage_half(lds, off, src, row0, kofs, coh)
#define PF_ISSUE(src) \
  do { if (coh) half_issue<true>(src, row0, pf); \
       else     half_issue<false>(src, row0, pf); } while (0)

__global__ void __launch_bounds__(NTHR, 2) rnn_ae(
    const float* __restrict__ x, const float* __restrict__ emb,
    const float* __restrict__ ew_ih0, const float* __restrict__ ew_ihr,
    const float* __restrict__ ew_hh, const float* __restrict__ eb_ih,
    const float* __restrict__ eb_hh,
    const float* __restrict__ dw_ih, const float* __restrict__ dw_hh,
    const float* __restrict__ db_ih, const float* __restrict__ db_hh,
    const float* __restrict__ projw,
    float* __restrict__ out, float* __restrict__ ws) {
  extern __shared__ float lds[];

  const int tid = threadIdx.x;
  const int bid = blockIdx.x;
  const int c   = tid >> 6;      // wave = col-pair 0..7
  const int ks  = tid & 63;      // k-lane 0..63

  int* flags  = (int*)ws;            // line-spread phase flags
  int* gctr   = (int*)ws + 8192;
  int* xcdtab = (int*)ws + 8704;
  float* h0  = ws + WS_INT_FLOATS;
  float* h1  = h0 + 2 * HPAR;
  float* h2  = h1 + 2 * HPAR;
  float* e0  = h2 + 2 * HPAR;
  float* e1  = e0 + 2 * HPAR;
  float* e2  = e1 + 2 * HPAR;
  float* xfb = e2 + 2 * HPAR;
  int ph = 0;

  // ------------- publish my XCD id ---------------------------------------
  unsigned xcc;
  asm volatile("s_getreg_b32 %0, hwreg(HW_REG_XCC_ID)" : "=s"(xcc));
  if (tid == 0)
    __hip_atomic_store(xcdtab + bid, (int)xcc, __ATOMIC_RELAXED,
                       __HIP_MEMORY_SCOPE_AGENT);

  // ------------- init: zero LDS, zero parity-1 h (bid-based cover) --------
  for (int i = tid; i < LDS_FLOATS; i += NTHR) lds[i] = 0.f;
  {
    const int zg = bid & 7, zcb = bid >> 3;
    for (int i = zcb * NTHR + tid; i < RPG * HH; i += WPG * NTHR) {
      const int r = i >> 9, cc = i & 511;
      const size_t o = HPAR + (size_t)(zg * RPG + r) * HH + cc;
      gst(h0 + o, 0.f); gst(h1 + o, 0.f); gst(h2 + o, 0.f);
    }
  }

  gbar_all(gctr);

  // ------------- XCD-aware regrouping (census; proven in R4/R8) -----------
  int g, cb, coh;
  {
    int* ldsX = (int*)(lds + IN1_OFF);       // scratch; IN1 region is fully
                                             // overwritten before first read
    if (tid < NWG)
      ldsX[tid] = __hip_atomic_load(xcdtab + tid, __ATOMIC_RELAXED,
                                    __HIP_MEMORY_SCOPE_AGENT);
    __syncthreads();
    const int myx = ldsX[bid] & 7;
    unsigned long long cnt = 0;
    int rank = 0;
    for (int b = 0; b < NWG; ++b) {
      const int xb = ldsX[b] & 7;
      cnt += 1ull << (xb * 8);
      if (b < bid && xb == myx) ++rank;
    }
    if (cnt == 0x2020202020202020ull) {      // all 8 XCDs have exactly 32
      g = myx; cb = rank; coh = 1;
    } else {
      g = bid & 7; cb = bid >> 3;
      coh = 1;
      const int x0 = ldsX[g] & 7;
      for (int j = 1; j < WPG; ++j)
        coh &= ((ldsX[g + 8 * j] & 7) == x0);
    }
    __syncthreads();                         // done with ldsX
  }
  const int row0 = g * RPG;
  const int col0 = cb * CPW;
  const int colA = col0 + 2 * c;
  const int colB = colA + 1;

  // ------------- load enc weights (depend on remapped col) ----------------
  float wA0[16], wB0[16], wA1[16], wB1[16], wA2[16], wB2[16];
  float bA0, bB0, bA1, bB1, bA2, bB2;
  load_wq0(wA0, ew_ih0, ew_hh, colA, ks);
  load_wq0(wB0, ew_ih0, ew_hh, colB, ks);
  load_wq(wA1, ew_ihr,                ew_hh + (size_t)HH * HH,     colA, ks);
  load_wq(wB1, ew_ihr,                ew_hh + (size_t)HH * HH,     colB, ks);
  load_wq(wA2, ew_ihr + (size_t)HH * HH, ew_hh + (size_t)2 * HH * HH, colA, ks);
  load_wq(wB2, ew_ihr + (size_t)HH * HH, ew_hh + (size_t)2 * HH * HH, colB, ks);
  bA0 = eb_ih[0*HH + colA] + eb_hh[0*HH + colA];
  bB0 = eb_ih[0*HH + colB] + eb_hh[0*HH + colB];
  bA1 = eb_ih[1*HH + colA] + eb_hh[1*HH + colA];
  bB1 = eb_ih[1*HH + colB] + eb_hh[1*HH + colB];
  bA2 = eb_ih[2*HH + colA] + eb_hh[2*HH + colA];
  bB2 = eb_ih[2*HH + colB] + eb_hh[2*HH + colB];

  // ------------- encoder: fused 3-layer pipeline, NT+2 rounds (R8 form) ---
  for (int s = 0; s < NT + 2; ++s) {
    const int t = s, t1 = s - 1, t2 = s - 2;
    float4 v0[2], v1a[2], v1b[2], v2a[2], v2b[2];
    // batched issue: ALL inputs of this round are pre-barrier data
    if (s < NT) {
      if (coh) half_issue<true>(h0 + ((t&1)^1) * HPAR, row0, v0);
      else     half_issue<false>(h0 + ((t&1)^1) * HPAR, row0, v0);
    }
    if (s >= 1 && s < NT + 1) {
      if (coh) { half_issue<true>(h0 + (t1&1) * HPAR, row0, v1a);
                 half_issue<true>(h1 + ((t1&1)^1) * HPAR, row0, v1b); }
      else     { half_issue<false>(h0 + (t1&1) * HPAR, row0, v1a);
                 half_issue<false>(h1 + ((t1&1)^1) * HPAR, row0, v1b); }
    }
    if (s >= 2) {
      if (coh) { half_issue<true>(h1 + (t2&1) * HPAR, row0, v2a);
                 half_issue<true>(h2 + ((t2&1)^1) * HPAR, row0, v2b); }
      else     { half_issue<false>(h1 + (t2&1) * HPAR, row0, v2a);
                 half_issue<false>(h2 + ((t2&1)^1) * HPAR, row0, v2b); }
    }
    asm volatile("s_waitcnt vmcnt(0)" ::: "memory");
    __builtin_amdgcn_sched_barrier(0);

    if (s < NT) {                    // l0 tile: emb + hprev (into IN0)
      half_commit(lds, IN0_OFF, 64, v0);
      if (tid < 128) {
        const int r = tid >> 4, i8 = tid & 15;
        const float* xr = x + ((size_t)(row0 + r) * NT + t) * NV;
        const float a0 = xr[0], a1 = xr[1], a2 = xr[2], a3 = xr[3];
        int idx = 0; float m = a0;
        if (a1 > m) { m = a1; idx = 1; }
        if (a2 > m) { m = a2; idx = 2; }
        if (a3 > m) { m = a3; idx = 3; }
        const int k = i8 << 2;
        *(float4*)(lds + IN0_OFF + r * 1024 + k) =
            *(const float4*)(emb + idx * ED + k);
      }
    }
    if (s >= 1 && s < NT + 1) {
      half_commit(lds, IN1_OFF, 0,   v1a);
      half_commit(lds, IN1_OFF, 512, v1b);
    }
    if (s < NT)
      layer_tile(lds, IN0_OFF, wA0, wB0, bA0, bB0,
                 h0 + (t&1) * HPAR, nullptr, row0, colA, coh);
    if (s >= 1 && s < NT + 1)
      layer_tile(lds, IN1_OFF, wA1, wB1, bA1, bB1,
                 h1 + (t1&1) * HPAR, nullptr, row0, colA, coh);
    if (s >= 2) {                    // reuse IN1 (l1's post-read sync guards)
      half_commit(lds, IN1_OFF, 0,   v2a);
      half_commit(lds, IN1_OFF, 512, v2b);
      layer_tile(lds, IN1_OFF, wA2, wB2, bA2, bB2,
                 h2 + (t2&1) * HPAR, nullptr, row0, colA, coh);
    }
    gbar(flags, g, cb, ++ph);
  }

  // ------------- transition: flip finals -> dec h0, load dec weights ------
  for (int i = cb * NTHR + tid; i < RPG * HH; i += WPG * NTHR) {
    const int r = i >> 9, cc = i & 511;
    const size_t o = HPAR + (size_t)(row0 + r) * HH + cc;
    const float a = gld(h2 + o);
    const float b = gld(h1 + o);
    const float cv = gld(h0 + o);
    if (coh) { e0[o] = a; e1[o] = b; e2[o] = cv; xfb[o] = 0.f; }
    else     { gst(e0 + o, a); gst(e1 + o, b); gst(e2 + o, cv); gst(xfb + o, 0.f); }
  }
  load_wq(wA0, dw_ih,                     dw_hh,                     colA, ks);
  load_wq(wB0, dw_ih,                     dw_hh,                     colB, ks);
  load_wq(wA1, dw_ih + (size_t)HH * HH,   dw_hh + (size_t)HH * HH,   colA, ks);
  load_wq(wB1, dw_ih + (size_t)HH * HH,   dw_hh + (size_t)HH * HH,   colB, ks);
  load_wq(wA2, dw_ih + (size_t)2*HH*HH,   dw_hh + (size_t)2*HH*HH,   colA, ks);
  load_wq(wB2, dw_ih + (size_t)2*HH*HH,   dw_hh + (size_t)2*HH*HH,   colB, ks);
  bA0 = db_ih[0*HH + colA] + db_hh[0*HH + colA];
  bB0 = db_ih[0*HH + colB] + db_hh[0*HH + colB];
  bA1 = db_ih[1*HH + colA] + db_hh[1*HH + colA];
  bB1 = db_ih[1*HH + colB] + db_hh[1*HH + colB];
  bA2 = db_ih[2*HH + colA] + db_hh[2*HH + colA];
  bB2 = db_ih[2*HH + colB] + db_hh[2*HH + colB];
  gbar(flags, g, cb, ++ph);

  // ------------- decoder t = 0 (peeled, original full-gbar structure) -----
  float4 pf[2];
  {
    const int p = 0, q = 1;
    STG(IN1_OFF, e0 + q * HPAR, 512);
    STG(IN1_OFF, xfb + q * HPAR, 0);
    __syncthreads();
    layer_tile(lds, IN1_OFF, wA0, wB0, bA0, bB0, e0 + p * HPAR, nullptr,
               row0, colA, coh);
    PF_ISSUE(e1 + q * HPAR);
    gbar(flags, g, cb, ++ph);

    half_commit(lds, IN1_OFF, 512, pf);
    STG(IN1_OFF, e0 + p * HPAR, 0);
    __syncthreads();
    layer_tile(lds, IN1_OFF, wA1, wB1, bA1, bB1, e1 + p * HPAR, nullptr,
               row0, colA, coh);
    PF_ISSUE(e2 + q * HPAR);
    gbar(flags, g, cb, ++ph);

    half_commit(lds, IN1_OFF, 512, pf);
    STG(IN1_OFF, e1 + p * HPAR, 0);
    __syncthreads();
    layer_tile(lds, IN1_OFF, wA2, wB2, bA2, bB2, e2 + p * HPAR,
               xfb + p * HPAR, row0, colA, coh);
    PF_ISSUE(e0 + p * HPAR);                 // t=1 l0's hprev (q' = p = 0)
    gbar(flags, g, cb, ++ph);
  }

  // ------------- decoder t >= 1: split phases (hh-compute hides the wait) -
  for (int t = 1; t < NT; ++t) {
    const int p = t & 1, q = p ^ 1;

    // ---- layer 0: cur = xfb[q], hprev = e0[q] (pf) ----
    PF_DRAIN();                              // pf regs valid before commit
    half_commit(lds, IN1_OFF, 512, pf);      // hprev -> hh half
    __syncthreads();
    float a0[16]; zero16(a0);
    tile_acc2(a0, lds, IN1_OFF, 2, wA0, wB0);   // hh compute while peers finish
    gbar_wait(flags, g, ph);                    // peers' xfb(t-1) now in L2
    STG(IN1_OFF, xfb + q * HPAR, 0);
    __syncthreads();
    tile_acc2(a0, lds, IN1_OFF, 0, wA0, wB0);   // ih half
    tile_finish(a0, bA0, bB0, e0 + p * HPAR, nullptr, row0, colA, coh);
    gbar_arrive(flags, g, cb, ++ph);            // drain h stores, post flag
    // proj AFTER the flag: off the pre-flag serial chain. Reads IN1[0..511]
    // of this phase's xfb tile; next overwrite of that region is 2 syncs
    // away in the next phase (wave0 participates in both) -> safe.
    if (cb < 8 && tid < 64)
      proj_row(lds, IN1_OFF, cb, projw, out, row0 + cb, t - 1);
    PF_ISSUE(e1 + q * HPAR);                    // flies across next phase top

    // ---- layer 1: cur = e0[p], hprev = e1[q] (pf) ----
    PF_DRAIN();
    half_commit(lds, IN1_OFF, 512, pf);
    __syncthreads();
    float a1[16]; zero16(a1);
    tile_acc2(a1, lds, IN1_OFF, 2, wA1, wB1);
    gbar_wait(flags, g, ph);
    STG(IN1_OFF, e0 + p * HPAR, 0);
    __syncthreads();
    tile_acc2(a1, lds, IN1_OFF, 0, wA1, wB1);
    tile_finish(a1, bA1, bB1, e1 + p * HPAR, nullptr, row0, colA, coh);
    gbar_arrive(flags, g, cb, ++ph);
    PF_ISSUE(e2 + q * HPAR);

    // ---- layer 2: cur = e1[p], hprev = e2[q] (pf) ----
    PF_DRAIN();
    half_commit(lds, IN1_OFF, 512, pf);
    __syncthreads();
    float a2[16]; zero16(a2);
    tile_acc2(a2, lds, IN1_OFF, 2, wA2, wB2);
    gbar_wait(flags, g, ph);
    STG(IN1_OFF, e1 + p * HPAR, 0);
    __syncthreads();
    tile_acc2(a2, lds, IN1_OFF, 0, wA2, wB2);
    tile_finish(a2, bA2, bB2, e2 + p * HPAR, xfb + p * HPAR, row0, colA, coh);
    gbar_arrive(flags, g, cb, ++ph);
    PF_ISSUE(e0 + p * HPAR);                    // next step l0's hprev (q' = p)
  }

  // ------------- tail projection for t = NT-1 -----------------------------
  gbar_wait(flags, g, ph);                      // peers' xfb(t=NT-1) ready
  STG(IN1_OFF, xfb + ((NT - 1) & 1) * HPAR, 0);
  __syncthreads();
  if (cb < 8 && tid < 64)
    proj_row(lds, IN1_OFF, cb, projw, out, row0 + cb, NT - 1);
}

extern "C" void kernel_launch(void* const* d_in, const int* in_sizes, int n_in,
                              void* d_out, int out_size, void* d_ws, size_t ws_size,
                              hipStream_t stream) {
  const float* x      = (const float*)d_in[0];
  const float* emb    = (const float*)d_in[1];
  const float* ew_ih0 = (const float*)d_in[2];
  const float* ew_ihr = (const float*)d_in[3];
  const float* ew_hh  = (const float*)d_in[4];
  const float* eb_ih  = (const float*)d_in[5];
  const float* eb_hh  = (const float*)d_in[6];
  const float* dw_ih  = (const float*)d_in[7];
  const float* dw_hh  = (const float*)d_in[8];
  const float* db_ih  = (const float*)d_in[9];
  const float* db_hh  = (const float*)d_in[10];
  const float* projw  = (const float*)d_in[11];
  float* out = (float*)d_out;
  float* ws  = (float*)d_ws;

  (void)hipMemsetAsync(d_ws, 0, WS_INT_FLOATS * 4, stream);

  // 96 KB dynamic LDS: 2 WGs cannot share a CU -> deterministic 1 WG/CU.
  (void)hipFuncSetAttribute((const void*)rnn_ae,
                            hipFuncAttributeMaxDynamicSharedMemorySize,
                            LDS_BYTES_ALLOC);

  rnn_ae<<<dim3(NWG), dim3(NTHR), LDS_BYTES_ALLOC, stream>>>(
      x, emb, ew_ih0, ew_ihr, ew_hh, eb_ih, eb_hh,
      dw_ih, dw_hh, db_ih, db_hh, projw, out, ws);
}

// Round 11
// 6664.182 us; speedup vs baseline: 1.0748x; 1.0161x over previous
//
#include <hip/hip_runtime.h>
#include <cmath>

#define HH 512
#define NV 4
#define ED 64
#define NB 64
#define NT 512

#define NWG  256
#define NTHR 512     // 8 col-pairs x 64 k-lanes; 8 waves -> 2 waves/SIMD
#define WPG  32      // workgroups per group
#define RPG  8       // batch rows per group
#define CPW  16      // output cols per WG

#define HPAR (NB * HH)          // parity stride in h buffers (32768 floats)

// LDS (floats): in0[8][1024] | in1[8][1024] | in2[8][1024] = 24576 fl = 96 KB
// (exactly the allocation that forces 1 WG/CU; encoder uses all 3 tiles,
//  decoder uses IN1 only)
#define IN0_OFF 0
#define IN1_OFF (8 * 1024)                // 8192
#define IN2_OFF (16 * 1024)               // 16384
#define LDS_FLOATS (IN2_OFF + 8 * 1024)   // 24576 used
#define LDS_BYTES_ALLOC 98304             // 96 KB

// ws ints (zeroed at launch):
//  [0 .. 8191]      per-WG phase flags, ONE 128B LINE EACH: flag(g,cb) at (g*32+cb)*32
//  [8192]           global one-shot counter
//  [8704 .. 8959]   xcdtab[bid]
#define WS_INT_FLOATS 9216
#define FLAG(g, cb) (((g) * 32 + (cb)) * 32)

// ---- device-coherent (MALL) scalar access -------------------------------
static __device__ __forceinline__ float gld(const float* p) {
  return __hip_atomic_load(p, __ATOMIC_RELAXED, __HIP_MEMORY_SCOPE_AGENT);
}
static __device__ __forceinline__ void gst(float* p, float v) {
  __hip_atomic_store(p, v, __ATOMIC_RELAXED, __HIP_MEMORY_SCOPE_AGENT);
}

// ---- group barrier: per-WG phase flag on its OWN cache line --------------
// Flags MUST stay agent-scope (MALL): narrower-scope poll loads can hit a
// stale L1-resident flag line forever (R1/R2 hang mechanism).
static __device__ __forceinline__ void gbar_arrive(int* flags, int g, int cb,
                                                   int ph) {
  asm volatile("s_waitcnt vmcnt(0)" ::: "memory");  // data stores at MALL/L2
  __syncthreads();
  if (threadIdx.x == 0)
    __hip_atomic_store(flags + FLAG(g, cb), ph, __ATOMIC_RELAXED,
                       __HIP_MEMORY_SCOPE_AGENT);
}
static __device__ __forceinline__ void gbar_wait(int* flags, int g, int ph) {
  if (threadIdx.x < 64) {
    const int* f = flags + FLAG(g, threadIdx.x & 31);
    while (__hip_atomic_load(f, __ATOMIC_RELAXED,
                             __HIP_MEMORY_SCOPE_AGENT) < ph)
      __builtin_amdgcn_s_sleep(1);
  }
  __syncthreads();
  asm volatile("" ::: "memory");
}
static __device__ __forceinline__ void gbar(int* flags, int g, int cb, int ph) {
  gbar_arrive(flags, g, cb, ph);
  gbar_wait(flags, g, ph);
}

static __device__ __forceinline__ void gbar_all(int* ctr) {
  asm volatile("s_waitcnt vmcnt(0)" ::: "memory");
  __syncthreads();
  if (threadIdx.x == 0) {
    __hip_atomic_fetch_add(ctr, 1, __ATOMIC_RELAXED, __HIP_MEMORY_SCOPE_AGENT);
    while (__hip_atomic_load(ctr, __ATOMIC_RELAXED,
                             __HIP_MEMORY_SCOPE_AGENT) < NWG)
      __builtin_amdgcn_s_sleep(1);
  }
  __syncthreads();
  asm volatile("" ::: "memory");
}

// ---- staging: one 8x512 half-tile = 2 x dwordx4 per thread --------------
template <bool COH>
static __device__ __forceinline__ void half_issue(const float* src, int row0,
                                                  float4 (&v)[2]) {
#pragma unroll
  for (int j = 0; j < 2; ++j) {
    const int qq = threadIdx.x + NTHR * j;
    const int row = qq >> 7, kq = qq & 127;
    const float* p = src + (size_t)(row0 + row) * HH + (kq << 2);
    if (COH) asm volatile("global_load_dwordx4 %0, %1, off sc0" : "=v"(v[j]) : "v"(p));
    else     asm volatile("global_load_dwordx4 %0, %1, off sc0 sc1" : "=v"(v[j]) : "v"(p));
  }
}
static __device__ __forceinline__ void half_commit(float* lds, int off,
                                                   int kofs, const float4 (&v)[2]) {
#pragma unroll
  for (int j = 0; j < 2; ++j) {
    const int qq = threadIdx.x + NTHR * j;
    const int row = qq >> 7, kq = qq & 127;
    *(float4*)(lds + off + row * 1024 + kofs + (kq << 2)) = v[j];
  }
}
static __device__ __forceinline__ void stage_half(float* lds, int off,
                                                  const float* src, int row0,
                                                  int kofs, int coh) {
  float4 v[2];
  if (coh) half_issue<true>(src, row0, v);
  else     half_issue<false>(src, row0, v);
  asm volatile("s_waitcnt vmcnt(0)" ::: "memory");
  __builtin_amdgcn_sched_barrier(0);
  half_commit(lds, off, kofs, v);
}

// pf loads are inline-asm: the compiler's waitcnt bookkeeping does NOT
// cover them. ALWAYS drain before committing pf registers to LDS.
#define PF_DRAIN() \
  do { asm volatile("s_waitcnt vmcnt(0)" ::: "memory"); \
       __builtin_amdgcn_sched_barrier(0); } while (0)

// ---- weights: per thread, per col: 4 quads of 4 floats (k = q*256+ks*4) --
static __device__ __forceinline__ void unpk(float (&w)[16], int q, float4 v) {
  w[4*q+0] = v.x; w[4*q+1] = v.y; w[4*q+2] = v.z; w[4*q+3] = v.w;
}
// standard 1024-K layer: tile = [ih input (0..511) | hh input (512..1023)]
static __device__ __forceinline__ void load_wq(float (&w)[16], const float* ih,
                                               const float* hh, int col, int ks) {
  unpk(w, 0, *(const float4*)(ih + (size_t)col * HH + ks * 4));
  unpk(w, 1, *(const float4*)(ih + (size_t)col * HH + 256 + ks * 4));
  unpk(w, 2, *(const float4*)(hh + (size_t)col * HH + ks * 4));
  unpk(w, 3, *(const float4*)(hh + (size_t)col * HH + 256 + ks * 4));
}
// encoder l0: tile = [emb (0..63) | h (64..575) | ZERO (576..1023)]
static __device__ __forceinline__ void load_wq0(float (&w)[16], const float* e,
                                                const float* hh, int col, int ks) {
  const float4 z = make_float4(0.f, 0.f, 0.f, 0.f);
  unpk(w, 0, (ks < 16) ? *(const float4*)(e + (size_t)col * ED + ks * 4)
                       : *(const float4*)(hh + (size_t)col * HH + (ks * 4 - 64)));
  unpk(w, 1, *(const float4*)(hh + (size_t)col * HH + 192 + ks * 4));
  unpk(w, 2, (ks < 16) ? *(const float4*)(hh + (size_t)col * HH + 448 + ks * 4) : z);
  unpk(w, 3, z);
}

// ---- half-tile accumulate (quads q0, q0+1) ------------------------------
static __device__ __forceinline__ void tile_acc2(
    float (&a)[16], const float* lds, int tile_off, int q0,
    const float (&wA)[16], const float (&wB)[16]) {
  const int lane = threadIdx.x & 63;
  const float* base = lds + tile_off + lane * 4;
#pragma unroll
  for (int r = 0; r < 8; ++r) {
    const float* rb = base + r * 1024;
#pragma unroll
    for (int qq = 0; qq < 2; ++qq) {
      const int q = q0 + qq;
      const float4 iv = *(const float4*)(rb + q * 256);
      a[2*r+0] = fmaf(wA[4*q+0], iv.x, a[2*r+0]);
      a[2*r+0] = fmaf(wA[4*q+1], iv.y, a[2*r+0]);
      a[2*r+0] = fmaf(wA[4*q+2], iv.z, a[2*r+0]);
      a[2*r+0] = fmaf(wA[4*q+3], iv.w, a[2*r+0]);
      a[2*r+1] = fmaf(wB[4*q+0], iv.x, a[2*r+1]);
      a[2*r+1] = fmaf(wB[4*q+1], iv.y, a[2*r+1]);
      a[2*r+1] = fmaf(wB[4*q+2], iv.z, a[2*r+1]);
      a[2*r+1] = fmaf(wB[4*q+3], iv.w, a[2*r+1]);
    }
  }
}
static __device__ __forceinline__ void zero16(float (&a)[16]) {
#pragma unroll
  for (int v = 0; v < 16; ++v) a[v] = 0.f;
}

// ---- 17-shuffle in-wave split-reduce + tanh + store ----------------------
static __device__ __forceinline__ void tile_finish(
    float (&a)[16], float bA, float bB,
    float* dst, float* dst2, int row0, int colA, int coh) {
  const int lane = threadIdx.x & 63;
#pragma unroll
  for (int i = 0; i < 8; ++i) {
    const float send = (lane & 32) ? a[i] : a[i + 8];
    const float recv = __shfl_xor(send, 32);
    const float keep = (lane & 32) ? a[i + 8] : a[i];
    a[i] = keep + recv;
  }
#pragma unroll
  for (int i = 0; i < 4; ++i) {
    const float send = (lane & 16) ? a[i] : a[i + 4];
    const float recv = __shfl_xor(send, 16);
    const float keep = (lane & 16) ? a[i + 4] : a[i];
    a[i] = keep + recv;
  }
#pragma unroll
  for (int i = 0; i < 2; ++i) {
    const float send = (lane & 8) ? a[i] : a[i + 2];
    const float recv = __shfl_xor(send, 8);
    const float keep = (lane & 8) ? a[i + 2] : a[i];
    a[i] = keep + recv;
  }
  {
    const float send = (lane & 4) ? a[0] : a[1];
    const float recv = __shfl_xor(send, 4);
    const float keep = (lane & 4) ? a[1] : a[0];
    a[0] = keep + recv;
  }
  a[0] += __shfl_xor(a[0], 1);
  a[0] += __shfl_xor(a[0], 2);
  if ((lane & 3) == 0) {
    const int r  = ((lane >> 5) & 1) * 4 + ((lane >> 4) & 1) * 2 + ((lane >> 3) & 1);
    const int cc = (lane >> 2) & 1;
    const float h = tanhf(a[0] + (cc ? bB : bA));
    const size_t idx = (size_t)(row0 + r) * HH + colA + cc;
    if (coh) { dst[idx] = h; if (dst2) dst2[idx] = h; }
    else     { gst(dst + idx, h); if (dst2) gst(dst2 + idx, h); }
  }
}

// ---- no-sync layer pass (encoder; caller provides the sync fences) -------
static __device__ __forceinline__ void layer_pass(
    float* lds, int tile_off,
    const float (&wA)[16], const float (&wB)[16], float bA, float bB,
    float* dst, int row0, int colA, int coh) {
  float a[16];
  zero16(a);
  tile_acc2(a, lds, tile_off, 0, wA, wB);
  tile_acc2(a, lds, tile_off, 2, wA, wB);
  tile_finish(a, bA, bB, dst, nullptr, row0, colA, coh);
}

// ---- full layer tile (decoder t=0 peel) ----------------------------------
static __device__ __forceinline__ void layer_tile(
    float* lds, int tile_off,
    const float (&wA)[16], const float (&wB)[16], float bA, float bB,
    float* dst, float* dst2, int row0, int colA, int coh) {
  __syncthreads();                  // staging visible
  float a[16];
  zero16(a);
  tile_acc2(a, lds, tile_off, 0, wA, wB);
  tile_acc2(a, lds, tile_off, 2, wA, wB);
  __syncthreads();                  // all reads done -> tile reusable
  tile_finish(a, bA, bB, dst, dst2, row0, colA, coh);
}

// ---- projection + log_softmax for one batch row (wave0 of cb<8 WGs) -----
static __device__ __forceinline__ void proj_row(const float* lds, int tile_off,
                                                int r_local, const float* projw,
                                                float* out, int row, int tt) {
  const int lane = threadIdx.x;       // < 64
  const int v = lane & 3, kq = lane >> 2;
  float acc = 0.f;
#pragma unroll
  for (int i8 = 0; i8 < 8; ++i8) {
    const int k = (kq << 5) + (i8 << 2);
    const float4 iv = *(const float4*)(lds + tile_off + r_local * 1024 + k);
    const float4 wv = *(const float4*)(projw + (size_t)v * HH + k);
    acc = fmaf(iv.x, wv.x, acc);
    acc = fmaf(iv.y, wv.y, acc);
    acc = fmaf(iv.z, wv.z, acc);
    acc = fmaf(iv.w, wv.w, acc);
  }
  acc += __shfl_xor(acc, 4);
  acc += __shfl_xor(acc, 8);
  acc += __shfl_xor(acc, 16);
  acc += __shfl_xor(acc, 32);
  float m = fmaxf(acc, __shfl_xor(acc, 1));
  m = fmaxf(m, __shfl_xor(m, 2));
  const float e = expf(acc - m);
  float sum = e + __shfl_xor(e, 1);
  sum += __shfl_xor(sum, 2);
  const float res = acc - m - logf(sum);
  if (lane < 4) out[((size_t)row * NT + tt) * NV + lane] = res;
}

#define STG(off, src, kofs) stage_half(lds, off, src, row0, kofs, coh)
#define PF_ISSUE(src) \
  do { if (coh) half_issue<true>(src, row0, pf); \
       else     half_issue<false>(src, row0, pf); } while (0)

__global__ void __launch_bounds__(NTHR, 2) rnn_ae(
    const float* __restrict__ x, const float* __restrict__ emb,
    const float* __restrict__ ew_ih0, const float* __restrict__ ew_ihr,
    const float* __restrict__ ew_hh, const float* __restrict__ eb_ih,
    const float* __restrict__ eb_hh,
    const float* __restrict__ dw_ih, const float* __restrict__ dw_hh,
    const float* __restrict__ db_ih, const float* __restrict__ db_hh,
    const float* __restrict__ projw,
    float* __restrict__ out, float* __restrict__ ws) {
  extern __shared__ float lds[];

  const int tid = threadIdx.x;
  const int bid = blockIdx.x;
  const int c   = tid >> 6;      // wave = col-pair 0..7
  const int ks  = tid & 63;      // k-lane 0..63

  int* flags  = (int*)ws;            // line-spread phase flags
  int* gctr   = (int*)ws + 8192;
  int* xcdtab = (int*)ws + 8704;
  float* h0  = ws + WS_INT_FLOATS;
  float* h1  = h0 + 2 * HPAR;
  float* h2  = h1 + 2 * HPAR;
  float* e0  = h2 + 2 * HPAR;
  float* e1  = e0 + 2 * HPAR;
  float* e2  = e1 + 2 * HPAR;
  float* xfb = e2 + 2 * HPAR;
  int ph = 0;

  // ------------- publish my XCD id ---------------------------------------
  unsigned xcc;
  asm volatile("s_getreg_b32 %0, hwreg(HW_REG_XCC_ID)" : "=s"(xcc));
  if (tid == 0)
    __hip_atomic_store(xcdtab + bid, (int)xcc, __ATOMIC_RELAXED,
                       __HIP_MEMORY_SCOPE_AGENT);

  // ------------- init: zero LDS, zero parity-1 h (bid-based cover) --------
  for (int i = tid; i < LDS_FLOATS; i += NTHR) lds[i] = 0.f;
  {
    const int zg = bid & 7, zcb = bid >> 3;
    for (int i = zcb * NTHR + tid; i < RPG * HH; i += WPG * NTHR) {
      const int r = i >> 9, cc = i & 511;
      const size_t o = HPAR + (size_t)(zg * RPG + r) * HH + cc;
      gst(h0 + o, 0.f); gst(h1 + o, 0.f); gst(h2 + o, 0.f);
    }
  }

  gbar_all(gctr);

  // ------------- XCD-aware regrouping (census; proven in R4/R8) -----------
  int g, cb, coh;
  {
    int* ldsX = (int*)(lds + IN1_OFF);       // scratch; IN1 region is fully
                                             // overwritten before first read
    if (tid < NWG)
      ldsX[tid] = __hip_atomic_load(xcdtab + tid, __ATOMIC_RELAXED,
                                    __HIP_MEMORY_SCOPE_AGENT);
    __syncthreads();
    const int myx = ldsX[bid] & 7;
    unsigned long long cnt = 0;
    int rank = 0;
    for (int b = 0; b < NWG; ++b) {
      const int xb = ldsX[b] & 7;
      cnt += 1ull << (xb * 8);
      if (b < bid && xb == myx) ++rank;
    }
    if (cnt == 0x2020202020202020ull) {      // all 8 XCDs have exactly 32
      g = myx; cb = rank; coh = 1;
    } else {
      g = bid & 7; cb = bid >> 3;
      coh = 1;
      const int x0 = ldsX[g] & 7;
      for (int j = 1; j < WPG; ++j)
        coh &= ((ldsX[g + 8 * j] & 7) == x0);
    }
    __syncthreads();                         // done with ldsX
    if (tid < NWG) ldsX[tid] = 0;            // restore zeroed IN1 region
    __syncthreads();
  }
  const int row0 = g * RPG;
  const int col0 = cb * CPW;
  const int colA = col0 + 2 * c;
  const int colB = colA + 1;

  // ------------- load enc weights (depend on remapped col) ----------------
  float wA0[16], wB0[16], wA1[16], wB1[16], wA2[16], wB2[16];
  float bA0, bB0, bA1, bB1, bA2, bB2;
  load_wq0(wA0, ew_ih0, ew_hh, colA, ks);
  load_wq0(wB0, ew_ih0, ew_hh, colB, ks);
  load_wq(wA1, ew_ihr,                ew_hh + (size_t)HH * HH,     colA, ks);
  load_wq(wB1, ew_ihr,                ew_hh + (size_t)HH * HH,     colB, ks);
  load_wq(wA2, ew_ihr + (size_t)HH * HH, ew_hh + (size_t)2 * HH * HH, colA, ks);
  load_wq(wB2, ew_ihr + (size_t)HH * HH, ew_hh + (size_t)2 * HH * HH, colB, ks);
  bA0 = eb_ih[0*HH + colA] + eb_hh[0*HH + colA];
  bB0 = eb_ih[0*HH + colB] + eb_hh[0*HH + colB];
  bA1 = eb_ih[1*HH + colA] + eb_hh[1*HH + colA];
  bB1 = eb_ih[1*HH + colB] + eb_hh[1*HH + colB];
  bA2 = eb_ih[2*HH + colA] + eb_hh[2*HH + colA];
  bB2 = eb_ih[2*HH + colB] + eb_hh[2*HH + colB];

  // ------------- encoder: fused 3-layer pipeline, 3-tile rounds -----------
  // All 5 half-loads issued together (pre-barrier data), one drain, all
  // commits (IN0/IN1/IN2 disjoint), ONE sync, 3 back-to-back layer passes.
  // Read-before-next-write is guaranteed by gbar's internal syncs.
  for (int s = 0; s < NT + 2; ++s) {
    const int t = s, t1 = s - 1, t2 = s - 2;
    const bool l0a = s < NT;
    const bool l1a = (s >= 1) && (s < NT + 1);
    const bool l2a = s >= 2;
    float4 v0[2], v1a[2], v1b[2], v2a[2], v2b[2];
    if (l0a) {
      if (coh) half_issue<true>(h0 + ((t&1)^1) * HPAR, row0, v0);
      else     half_issue<false>(h0 + ((t&1)^1) * HPAR, row0, v0);
    }
    if (l1a) {
      if (coh) { half_issue<true>(h0 + (t1&1) * HPAR, row0, v1a);
                 half_issue<true>(h1 + ((t1&1)^1) * HPAR, row0, v1b); }
      else     { half_issue<false>(h0 + (t1&1) * HPAR, row0, v1a);
                 half_issue<false>(h1 + ((t1&1)^1) * HPAR, row0, v1b); }
    }
    if (l2a) {
      if (coh) { half_issue<true>(h1 + (t2&1) * HPAR, row0, v2a);
                 half_issue<true>(h2 + ((t2&1)^1) * HPAR, row0, v2b); }
      else     { half_issue<false>(h1 + (t2&1) * HPAR, row0, v2a);
                 half_issue<false>(h2 + ((t2&1)^1) * HPAR, row0, v2b); }
    }
    asm volatile("s_waitcnt vmcnt(0)" ::: "memory");
    __builtin_amdgcn_sched_barrier(0);

    if (l0a) {                       // l0 tile: emb + hprev (into IN0)
      half_commit(lds, IN0_OFF, 64, v0);
      if (tid < 128) {
        const int r = tid >> 4, i8 = tid & 15;
        const float* xr = x + ((size_t)(row0 + r) * NT + t) * NV;
        const float a0 = xr[0], a1 = xr[1], a2 = xr[2], a3 = xr[3];
        int idx = 0; float m = a0;
        if (a1 > m) { m = a1; idx = 1; }
        if (a2 > m) { m = a2; idx = 2; }
        if (a3 > m) { m = a3; idx = 3; }
        const int k = i8 << 2;
        *(float4*)(lds + IN0_OFF + r * 1024 + k) =
            *(const float4*)(emb + idx * ED + k);
      }
    }
    if (l1a) {
      half_commit(lds, IN1_OFF, 0,   v1a);
      half_commit(lds, IN1_OFF, 512, v1b);
    }
    if (l2a) {
      half_commit(lds, IN2_OFF, 0,   v2a);
      half_commit(lds, IN2_OFF, 512, v2b);
    }
    __syncthreads();                 // ALL staging visible, once

    if (l0a)
      layer_pass(lds, IN0_OFF, wA0, wB0, bA0, bB0,
                 h0 + (t&1) * HPAR, row0, colA, coh);
    if (l1a)
      layer_pass(lds, IN1_OFF, wA1, wB1, bA1, bB1,
                 h1 + (t1&1) * HPAR, row0, colA, coh);
    if (l2a)
      layer_pass(lds, IN2_OFF, wA2, wB2, bA2, bB2,
                 h2 + (t2&1) * HPAR, row0, colA, coh);

    gbar(flags, g, cb, ++ph);
  }

  // ------------- transition: flip finals -> dec h0, load dec weights ------
  for (int i = cb * NTHR + tid; i < RPG * HH; i += WPG * NTHR) {
    const int r = i >> 9, cc = i & 511;
    const size_t o = HPAR + (size_t)(row0 + r) * HH + cc;
    const float a = gld(h2 + o);
    const float b = gld(h1 + o);
    const float cv = gld(h0 + o);
    if (coh) { e0[o] = a; e1[o] = b; e2[o] = cv; xfb[o] = 0.f; }
    else     { gst(e0 + o, a); gst(e1 + o, b); gst(e2 + o, cv); gst(xfb + o, 0.f); }
  }
  load_wq(wA0, dw_ih,                     dw_hh,                     colA, ks);
  load_wq(wB0, dw_ih,                     dw_hh,                     colB, ks);
  load_wq(wA1, dw_ih + (size_t)HH * HH,   dw_hh + (size_t)HH * HH,   colA, ks);
  load_wq(wB1, dw_ih + (size_t)HH * HH,   dw_hh + (size_t)HH * HH,   colB, ks);
  load_wq(wA2, dw_ih + (size_t)2*HH*HH,   dw_hh + (size_t)2*HH*HH,   colA, ks);
  load_wq(wB2, dw_ih + (size_t)2*HH*HH,   dw_hh + (size_t)2*HH*HH,   colB, ks);
  bA0 = db_ih[0*HH + colA] + db_hh[0*HH + colA];
  bB0 = db_ih[0*HH + colB] + db_hh[0*HH + colB];
  bA1 = db_ih[1*HH + colA] + db_hh[1*HH + colA];
  bB1 = db_ih[1*HH + colB] + db_hh[1*HH + colB];
  bA2 = db_ih[2*HH + colA] + db_hh[2*HH + colA];
  bB2 = db_ih[2*HH + colB] + db_hh[2*HH + colB];
  gbar(flags, g, cb, ++ph);

  // ------------- decoder t = 0 (peeled, original full-gbar structure) -----
  float4 pf[2];
  {
    const int p = 0, q = 1;
    STG(IN1_OFF, e0 + q * HPAR, 512);
    STG(IN1_OFF, xfb + q * HPAR, 0);
    __syncthreads();
    layer_tile(lds, IN1_OFF, wA0, wB0, bA0, bB0, e0 + p * HPAR, nullptr,
               row0, colA, coh);
    PF_ISSUE(e1 + q * HPAR);
    gbar(flags, g, cb, ++ph);

    half_commit(lds, IN1_OFF, 512, pf);
    STG(IN1_OFF, e0 + p * HPAR, 0);
    __syncthreads();
    layer_tile(lds, IN1_OFF, wA1, wB1, bA1, bB1, e1 + p * HPAR, nullptr,
               row0, colA, coh);
    PF_ISSUE(e2 + q * HPAR);
    gbar(flags, g, cb, ++ph);

    half_commit(lds, IN1_OFF, 512, pf);
    STG(IN1_OFF, e1 + p * HPAR, 0);
    __syncthreads();
    layer_tile(lds, IN1_OFF, wA2, wB2, bA2, bB2, e2 + p * HPAR,
               xfb + p * HPAR, row0, colA, coh);
    PF_ISSUE(e0 + p * HPAR);                 // t=1 l0's hprev (q' = p = 0)
    gbar(flags, g, cb, ++ph);
  }

  // ------------- decoder t >= 1: split phases (hh-compute hides the wait) -
  for (int t = 1; t < NT; ++t) {
    const int p = t & 1, q = p ^ 1;

    // ---- layer 0: cur = xfb[q], hprev = e0[q] (pf) ----
    PF_DRAIN();                              // pf regs valid before commit
    half_commit(lds, IN1_OFF, 512, pf);      // hprev -> hh half
    __syncthreads();
    float a0[16]; zero16(a0);
    tile_acc2(a0, lds, IN1_OFF, 2, wA0, wB0);   // hh compute while peers finish
    gbar_wait(flags, g, ph);                    // peers' xfb(t-1) now in L2
    STG(IN1_OFF, xfb + q * HPAR, 0);
    __syncthreads();
    tile_acc2(a0, lds, IN1_OFF, 0, wA0, wB0);   // ih half
    tile_finish(a0, bA0, bB0, e0 + p * HPAR, nullptr, row0, colA, coh);
    gbar_arrive(flags, g, cb, ++ph);            // drain h stores, post flag
    // proj AFTER the flag: off the pre-flag serial chain. Reads IN1[0..511]
    // of this phase's xfb tile; next overwrite of that region is 2 syncs
    // away in the next phase (wave0 participates in both) -> safe.
    if (cb < 8 && tid < 64)
      proj_row(lds, IN1_OFF, cb, projw, out, row0 + cb, t - 1);
    PF_ISSUE(e1 + q * HPAR);                    // flies across next phase top

    // ---- layer 1: cur = e0[p], hprev = e1[q] (pf) ----
    PF_DRAIN();
    half_commit(lds, IN1_OFF, 512, pf);
    __syncthreads();
    float a1[16]; zero16(a1);
    tile_acc2(a1, lds, IN1_OFF, 2, wA1, wB1);
    gbar_wait(flags, g, ph);
    STG(IN1_OFF, e0 + p * HPAR, 0);
    __syncthreads();
    tile_acc2(a1, lds, IN1_OFF, 0, wA1, wB1);
    tile_finish(a1, bA1, bB1, e1 + p * HPAR, nullptr, row0, colA, coh);
    gbar_arrive(flags, g, cb, ++ph);
    PF_ISSUE(e2 + q * HPAR);

    // ---- layer 2: cur = e1[p], hprev = e2[q] (pf) ----
    PF_DRAIN();
    half_commit(lds, IN1_OFF, 512, pf);
    __syncthreads();
    float a2[16]; zero16(a2);
    tile_acc2(a2, lds, IN1_OFF, 2, wA2, wB2);
    gbar_wait(flags, g, ph);
    STG(IN1_OFF, e1 + p * HPAR, 0);
    __syncthreads();
    tile_acc2(a2, lds, IN1_OFF, 0, wA2, wB2);
    tile_finish(a2, bA2, bB2, e2 + p * HPAR, xfb + p * HPAR, row0, colA, coh);
    gbar_arrive(flags, g, cb, ++ph);
    PF_ISSUE(e0 + p * HPAR);                    // next step l0's hprev (q' = p)
  }

  // ------------- tail projection for t = NT-1 -----------------------------
  gbar_wait(flags, g, ph);                      // peers' xfb(t=NT-1) ready
  STG(IN1_OFF, xfb + ((NT - 1) & 1) * HPAR, 0);
  __syncthreads();
  if (cb < 8 && tid < 64)
    proj_row(lds, IN1_OFF, cb, projw, out, row0 + cb, NT - 1);
}

extern "C" void kernel_launch(void* const* d_in, const int* in_sizes, int n_in,
                              void* d_out, int out_size, void* d_ws, size_t ws_size,
                              hipStream_t stream) {
  const float* x      = (const float*)d_in[0];
  const float* emb    = (const float*)d_in[1];
  const float* ew_ih0 = (const float*)d_in[2];
  const float* ew_ihr = (const float*)d_in[3];
  const float* ew_hh  = (const float*)d_in[4];
  const float* eb_ih  = (const float*)d_in[5];
  const float* eb_hh  = (const float*)d_in[6];
  const float* dw_ih  = (const float*)d_in[7];
  const float* dw_hh  = (const float*)d_in[8];
  const float* db_ih  = (const float*)d_in[9];
  const float* db_hh  = (const float*)d_in[10];
  const float* projw  = (const float*)d_in[11];
  float* out = (float*)d_out;
  float* ws  = (float*)d_ws;

  (void)hipMemsetAsync(d_ws, 0, WS_INT_FLOATS * 4, stream);

  // 96 KB dynamic LDS: 2 WGs cannot share a CU -> deterministic 1 WG/CU.
  (void)hipFuncSetAttribute((const void*)rnn_ae,
                            hipFuncAttributeMaxDynamicSharedMemorySize,
                            LDS_BYTES_ALLOC);

  rnn_ae<<<dim3(NWG), dim3(NTHR), LDS_BYTES_ALLOC, stream>>>(
      x, emb, ew_ih0, ew_ihr, ew_hh, eb_ih, eb_hh,
      dw_ih, dw_hh, db_ih, db_hh, projw, out, ws);
}